// Round 3
// baseline (886.959 us; speedup 1.0000x reference)
//
#include <hip/hip_runtime.h>
#include <hip/hip_bf16.h>
#include <stdint.h>

#define D_MODEL 1024
#define D_FF    4096
#define N_EXP   8
#define TOPK    2
#define NTOK    8192
#define NASSIGN (NTOK*TOPK)

#define BM 256
#define BN 256
#define BK 64
#define THREADS 512

typedef __bf16 bf16_t;
typedef __attribute__((ext_vector_type(8))) bf16_t bf16x8;
typedef __attribute__((ext_vector_type(4))) float f32x4;

__device__ __forceinline__ unsigned short f2bf(float f) {
    bf16_t b = (bf16_t)f;
    return __builtin_bit_cast(unsigned short, b);
}

__device__ __forceinline__ void gload_lds16(const void* g, void* l) {
    __builtin_amdgcn_global_load_lds(
        (const __attribute__((address_space(1))) void*)g,
        (__attribute__((address_space(3))) void*)l, 16, 0, 0);
}

// ---------------- zero output + counts ----------------
__global__ void zero_out_kernel(float* __restrict__ out, int n, int* __restrict__ counts) {
    if (blockIdx.x == 0 && threadIdx.x < N_EXP) counts[threadIdx.x] = 0;
    int stride = gridDim.x * blockDim.x;
    float4 z = make_float4(0.f, 0.f, 0.f, 0.f);
    for (int i = blockIdx.x * blockDim.x + threadIdx.x; i < n / 4; i += stride)
        ((float4*)out)[i] = z;
}

// ---------------- fp32 -> bf16 convert ----------------
__global__ void cvt_bf16_kernel(const float* __restrict__ in, unsigned short* __restrict__ outp, int n) {
    int stride = gridDim.x * blockDim.x;
    for (int i = blockIdx.x * blockDim.x + threadIdx.x; i < n / 4; i += stride) {
        float4 v = ((const float4*)in)[i];
        ushort4 o;
        o.x = f2bf(v.x); o.y = f2bf(v.y); o.z = f2bf(v.z); o.w = f2bf(v.w);
        ((ushort4*)outp)[i] = o;
    }
}

// ---------------- router ----------------
__global__ __launch_bounds__(64) void router_kernel(
        const float* __restrict__ x, const float* __restrict__ gw,
        int* __restrict__ counts, int* __restrict__ ltok, float* __restrict__ lw) {
    int n = blockIdx.x;
    int lane = threadIdx.x;
    const float* xr = x + (size_t)n * D_MODEL;
    float acc[N_EXP];
    #pragma unroll
    for (int e = 0; e < N_EXP; e++) acc[e] = 0.f;
    for (int d = lane; d < D_MODEL; d += 64) {
        float xv = xr[d];
        #pragma unroll
        for (int e = 0; e < N_EXP; e++) acc[e] += xv * gw[e * D_MODEL + d];
    }
    #pragma unroll
    for (int e = 0; e < N_EXP; e++) {
        #pragma unroll
        for (int off = 32; off > 0; off >>= 1)
            acc[e] += __shfl_down(acc[e], off);
    }
    if (lane == 0) {
        float mx = acc[0];
        #pragma unroll
        for (int e = 1; e < N_EXP; e++) mx = fmaxf(mx, acc[e]);
        float p[N_EXP];
        float s = 0.f;
        #pragma unroll
        for (int e = 0; e < N_EXP; e++) { p[e] = expf(acc[e] - mx); s += p[e]; }
        float inv = 1.f / s;
        #pragma unroll
        for (int e = 0; e < N_EXP; e++) p[e] *= inv;
        int i0 = 0;
        #pragma unroll
        for (int e = 1; e < N_EXP; e++) if (p[e] > p[i0]) i0 = e;
        int i1 = (i0 == 0) ? 1 : 0;
        #pragma unroll
        for (int e = 0; e < N_EXP; e++) if (e != i0 && p[e] > p[i1]) i1 = e;
        float s2 = p[i0] + p[i1] + 1e-9f;
        float w0 = p[i0] / s2, w1 = p[i1] / s2;
        int pos0 = atomicAdd(&counts[i0], 1);
        ltok[i0 * NTOK + pos0] = n; lw[i0 * NTOK + pos0] = w0;
        int pos1 = atomicAdd(&counts[i1], 1);
        ltok[i1 * NTOK + pos1] = n; lw[i1 * NTOK + pos1] = w1;
    }
}

// ---------------- exclusive scan over 8 expert counts ----------------
__global__ void scan_kernel(const int* __restrict__ counts, int* __restrict__ offs) {
    if (threadIdx.x == 0 && blockIdx.x == 0) {
        int s = 0;
        for (int e = 0; e < N_EXP; e++) { offs[e] = s; s += counts[e]; }
    }
}

// =====================================================================
// Phased 256x256 grouped GEMM. T2 swizzle (conflicts=0, verified r2) +
// counted vmcnt + setprio. NEW (r3): expert-clustered XCD mapping —
// raw block i lands on XCD i%8 (HK/m157 assumption), so decode
// e = i&7: all of expert e's blocks co-reside on XCD e. Their K-lockstep
// live slice (~384 KB/K-tile) fits the 4 MB L2 -> stage DMA is served at
// L2 latency instead of L3/HBM latency (the r2 stall).
// =====================================================================

// GEMM1: h = relu(X_gathered @ W1[e]^T + b1[e])
__global__ __launch_bounds__(THREADS, 2) void gemm1_kernel(
        const unsigned short* __restrict__ xb, const unsigned short* __restrict__ w1b,
        const float* __restrict__ b1,
        const int* __restrict__ counts, const int* __restrict__ offs,
        const int* __restrict__ ltok,
        unsigned short* __restrict__ hb) {
    const int NTN = D_FF / BN;   // 16
    int b = blockIdx.x;
    int e = b & 7;               // XCD-clustered: expert e -> XCD e
    int r = b >> 3;
    int mt = r / NTN;
    int nt = r % NTN;
    int cnt = counts[e];
    if (mt * BM >= cnt) return;

    __shared__ __align__(16) unsigned short As[2][BM * BK];   // 64 KB
    __shared__ __align__(16) unsigned short Bs[2][BN * BK];   // 64 KB

    int t = threadIdx.x;
    int lane = t & 63, w = t >> 6;     // 8 waves
    int wr = w >> 2, wc = w & 3;       // 2 x 4

    int srow = t >> 3;                       // 0..63
    int schunk = (t & 7) ^ (srow & 7);
    const unsigned short* aptr[4];
    const unsigned short* bptr[4];
    #pragma unroll
    for (int j = 0; j < 4; j++) {
        int rr = srow + j * 64;
        int slot = mt * BM + rr;
        int cs = slot < cnt ? slot : (cnt - 1);
        int tok = ltok[e * NTOK + cs];
        aptr[j] = xb + (size_t)tok * D_MODEL + schunk * 8;
        bptr[j] = w1b + ((size_t)e * D_FF + nt * BN + rr) * D_MODEL + schunk * 8;
    }

    auto stage = [&](int buf, int k0) {
        #pragma unroll
        for (int j = 0; j < 4; j++) {
            gload_lds16(aptr[j] + k0, (char*)&As[buf][0] + j * 8192 + w * 1024);
            gload_lds16(bptr[j] + k0, (char*)&Bs[buf][0] + j * 8192 + w * 1024);
        }
    };

    int arow_base = wr * 128 + (lane & 15);
    int brow_base = wc * 64 + (lane & 15);
    int ch[2];
    #pragma unroll
    for (int ks = 0; ks < 2; ks++)
        ch[ks] = ((ks * 4 + (lane >> 4)) ^ (lane & 7)) << 4;

    f32x4 acc[8][4];
    #pragma unroll
    for (int m = 0; m < 8; m++)
        #pragma unroll
        for (int n = 0; n < 4; n++)
            acc[m][n] = (f32x4){0.f, 0.f, 0.f, 0.f};

    const int NT = D_MODEL / BK;   // 16
    stage(0, 0);
    stage(1, BK);
    asm volatile("s_waitcnt vmcnt(8)" ::: "memory");
    __builtin_amdgcn_sched_barrier(0);
    __builtin_amdgcn_s_barrier();

    for (int tt = 0; tt < NT; ++tt) {
        int cur = tt & 1;
        const char* Ab = (const char*)&As[cur][0];
        const char* Bb = (const char*)&Bs[cur][0];
        bf16x8 bfr[2][4];
        #pragma unroll
        for (int p = 0; p < 4; ++p) {
            if (p == 0) {
                #pragma unroll
                for (int ks = 0; ks < 2; ++ks)
                    #pragma unroll
                    for (int n = 0; n < 4; ++n)
                        bfr[ks][n] = *(const bf16x8*)(Bb + (size_t)(brow_base + n * 16) * 128 + ch[ks]);
            }
            bf16x8 afr[2][2];
            #pragma unroll
            for (int ks = 0; ks < 2; ++ks)
                #pragma unroll
                for (int mm = 0; mm < 2; ++mm)
                    afr[ks][mm] = *(const bf16x8*)(Ab + (size_t)(arow_base + (p * 2 + mm) * 16) * 128 + ch[ks]);
            asm volatile("s_waitcnt lgkmcnt(0)" ::: "memory");
            __builtin_amdgcn_sched_barrier(0);
            __builtin_amdgcn_s_barrier();     // all waves' reads of buf[cur] this phase retired
            if (p == 3 && tt + 2 < NT)
                stage(cur, (tt + 2) * BK);    // safe: every wave past lgkmcnt(0)+barrier
            __builtin_amdgcn_s_setprio(1);
            #pragma unroll
            for (int ks = 0; ks < 2; ++ks)
                #pragma unroll
                for (int mm = 0; mm < 2; ++mm)
                    #pragma unroll
                    for (int n = 0; n < 4; ++n)
                        acc[p * 2 + mm][n] = __builtin_amdgcn_mfma_f32_16x16x32_bf16(
                            afr[ks][mm], bfr[ks][n], acc[p * 2 + mm][n], 0, 0, 0);
            __builtin_amdgcn_s_setprio(0);
            if (p == 3) {
                if (tt + 2 < NT) {
                    asm volatile("s_waitcnt vmcnt(8)" ::: "memory");
                } else {
                    asm volatile("s_waitcnt vmcnt(0)" ::: "memory");
                }
                __builtin_amdgcn_sched_barrier(0);
            }
            __builtin_amdgcn_s_barrier();
        }
    }

    // ---- epilogue: relu + bias, store bf16
    int hbase = offs[e];
    float biasv[4];
    #pragma unroll
    for (int n = 0; n < 4; ++n)
        biasv[n] = b1[e * D_FF + nt * BN + wc * 64 + n * 16 + (lane & 15)];
    #pragma unroll
    for (int m = 0; m < 8; ++m) {
        int s0 = mt * BM + wr * 128 + m * 16 + (lane >> 4) * 4;
        #pragma unroll
        for (int rq = 0; rq < 4; ++rq) {
            int s = s0 + rq;
            if (s < cnt) {
                size_t rowoff = (size_t)(hbase + s) * D_FF + nt * BN + wc * 64 + (lane & 15);
                #pragma unroll
                for (int n = 0; n < 4; ++n) {
                    float v = fmaxf(acc[m][n][rq] + biasv[n], 0.f);
                    hb[rowoff + n * 16] = f2bf(v);
                }
            }
        }
    }
}

// GEMM2: y = h @ W2[e]^T + b2[e]; weighted atomic scatter to out
__global__ __launch_bounds__(THREADS, 2) void gemm2_kernel(
        const unsigned short* __restrict__ hb, const unsigned short* __restrict__ w2b,
        const float* __restrict__ b2,
        const int* __restrict__ counts, const int* __restrict__ offs,
        const int* __restrict__ ltok, const float* __restrict__ lw,
        float* __restrict__ out) {
    const int NTN = D_MODEL / BN;  // 4
    int b = blockIdx.x;
    int e = b & 7;                 // XCD-clustered
    int r = b >> 3;
    int mt = r / NTN;
    int nt = r % NTN;
    int cnt = counts[e];
    if (mt * BM >= cnt) return;
    int hbase = offs[e];

    __shared__ __align__(16) unsigned short As[2][BM * BK];
    __shared__ __align__(16) unsigned short Bs[2][BN * BK];

    int t = threadIdx.x;
    int lane = t & 63, w = t >> 6;
    int wr = w >> 2, wc = w & 3;

    int srow = t >> 3;
    int schunk = (t & 7) ^ (srow & 7);
    const unsigned short* aptr[4];
    const unsigned short* bptr[4];
    #pragma unroll
    for (int j = 0; j < 4; j++) {
        int rr = srow + j * 64;
        int slot = mt * BM + rr;
        int cs = slot < cnt ? slot : (cnt - 1);
        aptr[j] = hb + (size_t)(hbase + cs) * D_FF + schunk * 8;
        bptr[j] = w2b + ((size_t)e * D_MODEL + nt * BN + rr) * D_FF + schunk * 8;
    }

    auto stage = [&](int buf, int k0) {
        #pragma unroll
        for (int j = 0; j < 4; j++) {
            gload_lds16(aptr[j] + k0, (char*)&As[buf][0] + j * 8192 + w * 1024);
            gload_lds16(bptr[j] + k0, (char*)&Bs[buf][0] + j * 8192 + w * 1024);
        }
    };

    int arow_base = wr * 128 + (lane & 15);
    int brow_base = wc * 64 + (lane & 15);
    int ch[2];
    #pragma unroll
    for (int ks = 0; ks < 2; ks++)
        ch[ks] = ((ks * 4 + (lane >> 4)) ^ (lane & 7)) << 4;

    f32x4 acc[8][4];
    #pragma unroll
    for (int m = 0; m < 8; m++)
        #pragma unroll
        for (int n = 0; n < 4; n++)
            acc[m][n] = (f32x4){0.f, 0.f, 0.f, 0.f};

    const int NT = D_FF / BK;   // 64
    stage(0, 0);
    stage(1, BK);
    asm volatile("s_waitcnt vmcnt(8)" ::: "memory");
    __builtin_amdgcn_sched_barrier(0);
    __builtin_amdgcn_s_barrier();

    for (int tt = 0; tt < NT; ++tt) {
        int cur = tt & 1;
        const char* Ab = (const char*)&As[cur][0];
        const char* Bb = (const char*)&Bs[cur][0];
        bf16x8 bfr[2][4];
        #pragma unroll
        for (int p = 0; p < 4; ++p) {
            if (p == 0) {
                #pragma unroll
                for (int ks = 0; ks < 2; ++ks)
                    #pragma unroll
                    for (int n = 0; n < 4; ++n)
                        bfr[ks][n] = *(const bf16x8*)(Bb + (size_t)(brow_base + n * 16) * 128 + ch[ks]);
            }
            bf16x8 afr[2][2];
            #pragma unroll
            for (int ks = 0; ks < 2; ++ks)
                #pragma unroll
                for (int mm = 0; mm < 2; ++mm)
                    afr[ks][mm] = *(const bf16x8*)(Ab + (size_t)(arow_base + (p * 2 + mm) * 16) * 128 + ch[ks]);
            asm volatile("s_waitcnt lgkmcnt(0)" ::: "memory");
            __builtin_amdgcn_sched_barrier(0);
            __builtin_amdgcn_s_barrier();
            if (p == 3 && tt + 2 < NT)
                stage(cur, (tt + 2) * BK);
            __builtin_amdgcn_s_setprio(1);
            #pragma unroll
            for (int ks = 0; ks < 2; ++ks)
                #pragma unroll
                for (int mm = 0; mm < 2; ++mm)
                    #pragma unroll
                    for (int n = 0; n < 4; ++n)
                        acc[p * 2 + mm][n] = __builtin_amdgcn_mfma_f32_16x16x32_bf16(
                            afr[ks][mm], bfr[ks][n], acc[p * 2 + mm][n], 0, 0, 0);
            __builtin_amdgcn_s_setprio(0);
            if (p == 3) {
                if (tt + 2 < NT) {
                    asm volatile("s_waitcnt vmcnt(8)" ::: "memory");
                } else {
                    asm volatile("s_waitcnt vmcnt(0)" ::: "memory");
                }
                __builtin_amdgcn_sched_barrier(0);
            }
            __builtin_amdgcn_s_barrier();
        }
    }

    // ---- epilogue: weighted atomic scatter
    int lbase = e * NTOK;
    float biasv[4];
    #pragma unroll
    for (int n = 0; n < 4; ++n)
        biasv[n] = b2[e * D_MODEL + nt * BN + wc * 64 + n * 16 + (lane & 15)];
    #pragma unroll
    for (int m = 0; m < 8; ++m) {
        int s0 = mt * BM + wr * 128 + m * 16 + (lane >> 4) * 4;
        #pragma unroll
        for (int rq = 0; rq < 4; ++rq) {
            int s = s0 + rq;
            if (s >= cnt) continue;
            int tok = ltok[lbase + s];
            float wgt = lw[lbase + s];
            float* orow = out + (size_t)tok * D_MODEL + nt * BN + wc * 64 + (lane & 15);
            #pragma unroll
            for (int n = 0; n < 4; ++n)
                atomicAdd(orow + n * 16, wgt * (acc[m][n][rq] + biasv[n]));
        }
    }
}

extern "C" void kernel_launch(void* const* d_in, const int* in_sizes, int n_in,
                              void* d_out, int out_size, void* d_ws, size_t ws_size,
                              hipStream_t stream) {
    const float* x  = (const float*)d_in[0];
    const float* gw = (const float*)d_in[1];
    const float* W1 = (const float*)d_in[2];
    const float* b1 = (const float*)d_in[3];
    const float* W2 = (const float*)d_in[4];
    const float* b2 = (const float*)d_in[5];
    float* out = (float*)d_out;

    char* ws = (char*)d_ws;
    size_t off = 0;
    auto alloc = [&](size_t bytes) -> char* {
        char* p = ws + off;
        off += (bytes + 255) & ~(size_t)255;
        return p;
    };
    unsigned short* xb  = (unsigned short*)alloc((size_t)NTOK * D_MODEL * 2);
    unsigned short* w1b = (unsigned short*)alloc((size_t)N_EXP * D_FF * D_MODEL * 2);
    unsigned short* w2b = (unsigned short*)alloc((size_t)N_EXP * D_MODEL * D_FF * 2);
    unsigned short* hb  = (unsigned short*)alloc((size_t)NASSIGN * D_FF * 2);
    int*   counts = (int*)alloc(256);
    int*   offs   = (int*)alloc(256);
    int*   ltok   = (int*)alloc((size_t)N_EXP * NTOK * 4);
    float* lw     = (float*)alloc((size_t)N_EXP * NTOK * 4);

    zero_out_kernel<<<2048, 256, 0, stream>>>(out, out_size, counts);
    cvt_bf16_kernel<<<2048, 256, 0, stream>>>(x, xb, NTOK * D_MODEL);
    cvt_bf16_kernel<<<4096, 256, 0, stream>>>(W1, w1b, N_EXP * D_FF * D_MODEL);
    cvt_bf16_kernel<<<4096, 256, 0, stream>>>(W2, w2b, N_EXP * D_MODEL * D_FF);
    router_kernel<<<NTOK, 64, 0, stream>>>(x, gw, counts, ltok, lw);
    scan_kernel<<<1, 64, 0, stream>>>(counts, offs);
    gemm1_kernel<<<N_EXP * (NTOK / BM) * (D_FF / BN), THREADS, 0, stream>>>(
        xb, w1b, b1, counts, offs, ltok, hb);
    gemm2_kernel<<<N_EXP * (NTOK / BM) * (D_MODEL / BN), THREADS, 0, stream>>>(
        hb, w2b, b2, counts, offs, ltok, lw, out);
}

// Round 4
// 699.566 us; speedup vs baseline: 1.2679x; 1.2679x over previous
//
#include <hip/hip_runtime.h>
#include <hip/hip_bf16.h>
#include <stdint.h>

#define D_MODEL 1024
#define D_FF    4096
#define N_EXP   8
#define TOPK    2
#define NTOK    8192
#define NASSIGN (NTOK*TOPK)

#define BM 128
#define BN 128
#define BK 64
#define THREADS 256

typedef __bf16 bf16_t;
typedef __attribute__((ext_vector_type(8))) bf16_t bf16x8;
typedef __attribute__((ext_vector_type(4))) float f32x4;

__device__ __forceinline__ unsigned short f2bf(float f) {
    bf16_t b = (bf16_t)f;
    return __builtin_bit_cast(unsigned short, b);
}

__device__ __forceinline__ void gload_lds16(const void* g, void* l) {
    __builtin_amdgcn_global_load_lds(
        (const __attribute__((address_space(1))) void*)g,
        (__attribute__((address_space(3))) void*)l, 16, 0, 0);
}

// ---------------- zero output + counts ----------------
__global__ void zero_out_kernel(float* __restrict__ out, int n, int* __restrict__ counts) {
    if (blockIdx.x == 0 && threadIdx.x < N_EXP) counts[threadIdx.x] = 0;
    int stride = gridDim.x * blockDim.x;
    float4 z = make_float4(0.f, 0.f, 0.f, 0.f);
    for (int i = blockIdx.x * blockDim.x + threadIdx.x; i < n / 4; i += stride)
        ((float4*)out)[i] = z;
}

// ---------------- fp32 -> bf16 convert ----------------
__global__ void cvt_bf16_kernel(const float* __restrict__ in, unsigned short* __restrict__ outp, int n) {
    int stride = gridDim.x * blockDim.x;
    for (int i = blockIdx.x * blockDim.x + threadIdx.x; i < n / 4; i += stride) {
        float4 v = ((const float4*)in)[i];
        ushort4 o;
        o.x = f2bf(v.x); o.y = f2bf(v.y); o.z = f2bf(v.z); o.w = f2bf(v.w);
        ((ushort4*)outp)[i] = o;
    }
}

// ---------------- router ----------------
__global__ __launch_bounds__(64) void router_kernel(
        const float* __restrict__ x, const float* __restrict__ gw,
        int* __restrict__ counts, int* __restrict__ ltok, float* __restrict__ lw) {
    int n = blockIdx.x;
    int lane = threadIdx.x;
    const float* xr = x + (size_t)n * D_MODEL;
    float acc[N_EXP];
    #pragma unroll
    for (int e = 0; e < N_EXP; e++) acc[e] = 0.f;
    for (int d = lane; d < D_MODEL; d += 64) {
        float xv = xr[d];
        #pragma unroll
        for (int e = 0; e < N_EXP; e++) acc[e] += xv * gw[e * D_MODEL + d];
    }
    #pragma unroll
    for (int e = 0; e < N_EXP; e++) {
        #pragma unroll
        for (int off = 32; off > 0; off >>= 1)
            acc[e] += __shfl_down(acc[e], off);
    }
    if (lane == 0) {
        float mx = acc[0];
        #pragma unroll
        for (int e = 1; e < N_EXP; e++) mx = fmaxf(mx, acc[e]);
        float p[N_EXP];
        float s = 0.f;
        #pragma unroll
        for (int e = 0; e < N_EXP; e++) { p[e] = expf(acc[e] - mx); s += p[e]; }
        float inv = 1.f / s;
        #pragma unroll
        for (int e = 0; e < N_EXP; e++) p[e] *= inv;
        int i0 = 0;
        #pragma unroll
        for (int e = 1; e < N_EXP; e++) if (p[e] > p[i0]) i0 = e;
        int i1 = (i0 == 0) ? 1 : 0;
        #pragma unroll
        for (int e = 0; e < N_EXP; e++) if (e != i0 && p[e] > p[i1]) i1 = e;
        float s2 = p[i0] + p[i1] + 1e-9f;
        float w0 = p[i0] / s2, w1 = p[i1] / s2;
        int pos0 = atomicAdd(&counts[i0], 1);
        ltok[i0 * NTOK + pos0] = n; lw[i0 * NTOK + pos0] = w0;
        int pos1 = atomicAdd(&counts[i1], 1);
        ltok[i1 * NTOK + pos1] = n; lw[i1 * NTOK + pos1] = w1;
    }
}

// ---------------- exclusive scan over 8 expert counts ----------------
__global__ void scan_kernel(const int* __restrict__ counts, int* __restrict__ offs) {
    if (threadIdx.x == 0 && blockIdx.x == 0) {
        int s = 0;
        for (int e = 0; e < N_EXP; e++) { offs[e] = s; s += counts[e]; }
    }
}

// =====================================================================
// r4: back to m97 residency regime. 128x128 tile, 4 waves, SINGLE-buffered
// 32KB LDS, plain __syncthreads (compiler waits), 3 blocks/CU
// (__launch_bounds__(256,3)) -> inter-block overlap (m114) hides stage
// latency. Keep verified wins: T2 chunk-XOR swizzle (conflicts=0, r2) and
// expert->XCD clustering e=b&7 (FETCH -3x, r3). Block order idx=nt*NTM+mt
// so a CU's co-resident blocks (idx stride 32) share one W-panel.
// =====================================================================

// GEMM1: h = relu(X_gathered @ W1[e]^T + b1[e])
__global__ __launch_bounds__(THREADS, 3) void gemm1_kernel(
        const unsigned short* __restrict__ xb, const unsigned short* __restrict__ w1b,
        const float* __restrict__ b1,
        const int* __restrict__ counts, const int* __restrict__ offs,
        const int* __restrict__ ltok,
        unsigned short* __restrict__ hb) {
    const int NTM = NTOK / BM;   // 64 (worst case)
    int b = blockIdx.x;
    int e = b & 7;               // expert -> XCD
    int idx = b >> 3;
    int nt = idx / NTM;          // W-panel major: co-resident blocks share nt
    int mt = idx % NTM;
    int cnt = counts[e];
    if (mt * BM >= cnt) return;

    __shared__ __align__(16) unsigned short As[BM * BK];   // 16 KB
    __shared__ __align__(16) unsigned short Bs[BN * BK];   // 16 KB

    int t = threadIdx.x;
    int lane = t & 63, w = t >> 6;     // 4 waves
    int wr = w >> 1, wc = w & 1;       // 2 x 2

    // staging: thread -> row (t>>3)+j*32, slot t&7; source chunk = slot^(row&7)
    int srow = t >> 3;                       // 0..31
    int schunk = (t & 7) ^ (srow & 7);
    const unsigned short* aptr[4];
    const unsigned short* bptr[4];
    #pragma unroll
    for (int j = 0; j < 4; j++) {
        int rr = srow + j * 32;
        int slot = mt * BM + rr;
        int cs = slot < cnt ? slot : (cnt - 1);
        int tok = ltok[e * NTOK + cs];
        aptr[j] = xb + (size_t)tok * D_MODEL + schunk * 8;
        bptr[j] = w1b + ((size_t)e * D_FF + nt * BN + rr) * D_MODEL + schunk * 8;
    }
    char* As_b = (char*)As;
    char* Bs_b = (char*)Bs;

    // swizzled read offsets: row&7 == lane&7 for fragment rows
    int arow_base = wr * 64 + (lane & 15);
    int brow_base = wc * 64 + (lane & 15);
    int ch[2];
    #pragma unroll
    for (int ks = 0; ks < 2; ks++)
        ch[ks] = ((ks * 4 + (lane >> 4)) ^ (lane & 7)) << 4;

    f32x4 acc[4][4];
    #pragma unroll
    for (int m = 0; m < 4; m++)
        #pragma unroll
        for (int n = 0; n < 4; n++)
            acc[m][n] = (f32x4){0.f, 0.f, 0.f, 0.f};

    for (int k0 = 0; k0 < D_MODEL; k0 += BK) {
        #pragma unroll
        for (int j = 0; j < 4; j++) {
            gload_lds16(aptr[j] + k0, As_b + j * 4096 + t * 16);
            gload_lds16(bptr[j] + k0, Bs_b + j * 4096 + t * 16);
        }
        __syncthreads();
        bf16x8 af[2][4], bf[2][4];
        #pragma unroll
        for (int ks = 0; ks < 2; ks++) {
            #pragma unroll
            for (int m = 0; m < 4; m++)
                af[ks][m] = *(const bf16x8*)(As_b + (size_t)(arow_base + m * 16) * 128 + ch[ks]);
            #pragma unroll
            for (int n = 0; n < 4; n++)
                bf[ks][n] = *(const bf16x8*)(Bs_b + (size_t)(brow_base + n * 16) * 128 + ch[ks]);
        }
        #pragma unroll
        for (int ks = 0; ks < 2; ks++)
            #pragma unroll
            for (int m = 0; m < 4; m++)
                #pragma unroll
                for (int n = 0; n < 4; n++)
                    acc[m][n] = __builtin_amdgcn_mfma_f32_16x16x32_bf16(af[ks][m], bf[ks][n], acc[m][n], 0, 0, 0);
        __syncthreads();
    }

    // epilogue: relu + bias, store bf16
    int hbase = offs[e];
    float biasv[4];
    #pragma unroll
    for (int n = 0; n < 4; ++n)
        biasv[n] = b1[e * D_FF + nt * BN + wc * 64 + n * 16 + (lane & 15)];
    #pragma unroll
    for (int m = 0; m < 4; ++m) {
        int s0 = mt * BM + wr * 64 + m * 16 + (lane >> 4) * 4;
        #pragma unroll
        for (int rq = 0; rq < 4; ++rq) {
            int s = s0 + rq;
            if (s < cnt) {
                size_t rowoff = (size_t)(hbase + s) * D_FF + nt * BN + wc * 64 + (lane & 15);
                #pragma unroll
                for (int n = 0; n < 4; ++n) {
                    float v = fmaxf(acc[m][n][rq] + biasv[n], 0.f);
                    hb[rowoff + n * 16] = f2bf(v);
                }
            }
        }
    }
}

// GEMM2: y = h @ W2[e]^T + b2[e]; weighted atomic scatter to out
__global__ __launch_bounds__(THREADS, 3) void gemm2_kernel(
        const unsigned short* __restrict__ hb, const unsigned short* __restrict__ w2b,
        const float* __restrict__ b2,
        const int* __restrict__ counts, const int* __restrict__ offs,
        const int* __restrict__ ltok, const float* __restrict__ lw,
        float* __restrict__ out) {
    const int NTM = NTOK / BM;     // 64
    int b = blockIdx.x;
    int e = b & 7;
    int idx = b >> 3;
    int nt = idx / NTM;
    int mt = idx % NTM;
    int cnt = counts[e];
    if (mt * BM >= cnt) return;
    int hbase = offs[e];

    __shared__ __align__(16) unsigned short As[BM * BK];
    __shared__ __align__(16) unsigned short Bs[BN * BK];

    int t = threadIdx.x;
    int lane = t & 63, w = t >> 6;
    int wr = w >> 1, wc = w & 1;

    int srow = t >> 3;
    int schunk = (t & 7) ^ (srow & 7);
    const unsigned short* aptr[4];
    const unsigned short* bptr[4];
    #pragma unroll
    for (int j = 0; j < 4; j++) {
        int rr = srow + j * 32;
        int slot = mt * BM + rr;
        int cs = slot < cnt ? slot : (cnt - 1);
        aptr[j] = hb + (size_t)(hbase + cs) * D_FF + schunk * 8;
        bptr[j] = w2b + ((size_t)e * D_MODEL + nt * BN + rr) * D_FF + schunk * 8;
    }
    char* As_b = (char*)As;
    char* Bs_b = (char*)Bs;

    int arow_base = wr * 64 + (lane & 15);
    int brow_base = wc * 64 + (lane & 15);
    int ch[2];
    #pragma unroll
    for (int ks = 0; ks < 2; ks++)
        ch[ks] = ((ks * 4 + (lane >> 4)) ^ (lane & 7)) << 4;

    f32x4 acc[4][4];
    #pragma unroll
    for (int m = 0; m < 4; m++)
        #pragma unroll
        for (int n = 0; n < 4; n++)
            acc[m][n] = (f32x4){0.f, 0.f, 0.f, 0.f};

    for (int k0 = 0; k0 < D_FF; k0 += BK) {
        #pragma unroll
        for (int j = 0; j < 4; j++) {
            gload_lds16(aptr[j] + k0, As_b + j * 4096 + t * 16);
            gload_lds16(bptr[j] + k0, Bs_b + j * 4096 + t * 16);
        }
        __syncthreads();
        bf16x8 af[2][4], bf[2][4];
        #pragma unroll
        for (int ks = 0; ks < 2; ks++) {
            #pragma unroll
            for (int m = 0; m < 4; m++)
                af[ks][m] = *(const bf16x8*)(As_b + (size_t)(arow_base + m * 16) * 128 + ch[ks]);
            #pragma unroll
            for (int n = 0; n < 4; n++)
                bf[ks][n] = *(const bf16x8*)(Bs_b + (size_t)(brow_base + n * 16) * 128 + ch[ks]);
        }
        #pragma unroll
        for (int ks = 0; ks < 2; ks++)
            #pragma unroll
            for (int m = 0; m < 4; m++)
                #pragma unroll
                for (int n = 0; n < 4; n++)
                    acc[m][n] = __builtin_amdgcn_mfma_f32_16x16x32_bf16(af[ks][m], bf[ks][n], acc[m][n], 0, 0, 0);
        __syncthreads();
    }

    // epilogue: weighted atomic scatter
    int lbase = e * NTOK;
    float biasv[4];
    #pragma unroll
    for (int n = 0; n < 4; ++n)
        biasv[n] = b2[e * D_MODEL + nt * BN + wc * 64 + n * 16 + (lane & 15)];
    #pragma unroll
    for (int m = 0; m < 4; ++m) {
        int s0 = mt * BM + wr * 64 + m * 16 + (lane >> 4) * 4;
        #pragma unroll
        for (int rq = 0; rq < 4; ++rq) {
            int s = s0 + rq;
            if (s >= cnt) continue;
            int tok = ltok[lbase + s];
            float wgt = lw[lbase + s];
            float* orow = out + (size_t)tok * D_MODEL + nt * BN + wc * 64 + (lane & 15);
            #pragma unroll
            for (int n = 0; n < 4; ++n)
                atomicAdd(orow + n * 16, wgt * (acc[m][n][rq] + biasv[n]));
        }
    }
}

extern "C" void kernel_launch(void* const* d_in, const int* in_sizes, int n_in,
                              void* d_out, int out_size, void* d_ws, size_t ws_size,
                              hipStream_t stream) {
    const float* x  = (const float*)d_in[0];
    const float* gw = (const float*)d_in[1];
    const float* W1 = (const float*)d_in[2];
    const float* b1 = (const float*)d_in[3];
    const float* W2 = (const float*)d_in[4];
    const float* b2 = (const float*)d_in[5];
    float* out = (float*)d_out;

    char* ws = (char*)d_ws;
    size_t off = 0;
    auto alloc = [&](size_t bytes) -> char* {
        char* p = ws + off;
        off += (bytes + 255) & ~(size_t)255;
        return p;
    };
    unsigned short* xb  = (unsigned short*)alloc((size_t)NTOK * D_MODEL * 2);
    unsigned short* w1b = (unsigned short*)alloc((size_t)N_EXP * D_FF * D_MODEL * 2);
    unsigned short* w2b = (unsigned short*)alloc((size_t)N_EXP * D_MODEL * D_FF * 2);
    unsigned short* hb  = (unsigned short*)alloc((size_t)NASSIGN * D_FF * 2);
    int*   counts = (int*)alloc(256);
    int*   offs   = (int*)alloc(256);
    int*   ltok   = (int*)alloc((size_t)N_EXP * NTOK * 4);
    float* lw     = (float*)alloc((size_t)N_EXP * NTOK * 4);

    zero_out_kernel<<<2048, 256, 0, stream>>>(out, out_size, counts);
    cvt_bf16_kernel<<<2048, 256, 0, stream>>>(x, xb, NTOK * D_MODEL);
    cvt_bf16_kernel<<<4096, 256, 0, stream>>>(W1, w1b, N_EXP * D_FF * D_MODEL);
    cvt_bf16_kernel<<<4096, 256, 0, stream>>>(W2, w2b, N_EXP * D_MODEL * D_FF);
    router_kernel<<<NTOK, 64, 0, stream>>>(x, gw, counts, ltok, lw);
    scan_kernel<<<1, 64, 0, stream>>>(counts, offs);
    gemm1_kernel<<<N_EXP * (NTOK / BM) * (D_FF / BN), THREADS, 0, stream>>>(
        xb, w1b, b1, counts, offs, ltok, hb);
    gemm2_kernel<<<N_EXP * (NTOK / BM) * (D_MODEL / BN), THREADS, 0, stream>>>(
        hb, w2b, b2, counts, offs, ltok, lw, out);
}